// Round 1
// baseline (2818.732 us; speedup 1.0000x reference)
//
#include <hip/hip_runtime.h>

#define NBLK 256
#define BS   256
// ws layout (floats): [0..255] counter+pad, [256 .. 256+45*512) stats (45 slots x 8 reps x 64),
// [23296 .. 23296+65536) transposed end_conv2_w
#define STATS_F 256
#define W2T_F   23296

__device__ __forceinline__ void mish2(float v, float& mp, float& mn) {
  // mish(v) = v*tanh(softplus(v)) = v*(u^2+2u)/(u^2+2u+2), u=e^v
  // mish(-v) = -v*(2u+1)/(2u^2+2u+1)   (shares u)
  float vc = fminf(fmaxf(v, -30.f), 30.f);
  float u  = __expf(vc);
  float n1 = u * (u + 2.f);
  mp = v * n1 * __builtin_amdgcn_rcpf(n1 + 2.f);
  float n2 = fmaf(2.f, u, 1.f);
  float d2 = fmaf(2.f * u, u, n2);
  mn = -v * n2 * __builtin_amdgcn_rcpf(d2);
}

__device__ __forceinline__ void grid_sync(unsigned* cnt, unsigned target) {
  __syncthreads();               // drains each wave's vmem (atomics) before arrival
  if (threadIdx.x == 0) {
    __threadfence();             // release: writeback L2 (cross-XCD visibility)
    __hip_atomic_fetch_add(cnt, 1u, __ATOMIC_RELAXED, __HIP_MEMORY_SCOPE_AGENT);
    while (__hip_atomic_load(cnt, __ATOMIC_RELAXED, __HIP_MEMORY_SCOPE_AGENT) < target)
      __builtin_amdgcn_s_sleep(1);
    __threadfence();             // acquire: invalidate L1/L2 before stat reads
  }
  __syncthreads();
}

// Per-block reduce of 32 per-thread values -> 64 quantities (32 sums + 32 sumsq),
// atomically added into slot[rep*64 + q]. s_red is BS*32 floats, xor-swizzled.
__device__ __forceinline__ void block_reduce_stats(const float (&vals)[32],
    float* s_red, float* s_p2, float* slot, int t, int rep) {
  #pragma unroll
  for (int cc = 0; cc < 8; ++cc) {
    float4 v = make_float4(vals[cc*4+0], vals[cc*4+1], vals[cc*4+2], vals[cc*4+3]);
    *(float4*)(&s_red[t*32 + ((cc ^ (t & 7)) << 2)]) = v;  // conflict-free (2-way)
  }
  __syncthreads();
  {
    int q = t & 63, grp = t >> 6, c = q & 31;
    bool issq = (q >= 32);
    float acc = 0.f;
    #pragma clang loop unroll_count(8)
    for (int rr = 0; rr < 64; ++rr) {
      int row = grp * 64 + rr;
      float v = s_red[row*32 + ((((c >> 2) ^ (row & 7)) << 2) | (c & 3))];
      acc = fmaf(v, issq ? v : 1.f, acc);
    }
    s_p2[t] = acc;   // t == grp*64+q
  }
  __syncthreads();
  if (t < 64) {
    float tot = s_p2[t] + s_p2[t+64] + s_p2[t+128] + s_p2[t+192];
    unsafeAtomicAdd(&slot[rep*64 + t], tot);
  }
}

extern "C" __global__ void __launch_bounds__(BS, 1)
qnet_kernel(const float* __restrict__ xin,
            const float* __restrict__ start_w, const float* __restrict__ start_b,
            const float* __restrict__ gate_w,  const float* __restrict__ gate_b,
            const float* __restrict__ res_w,   const float* __restrict__ res_b,
            const float* __restrict__ bn_g,    const float* __restrict__ bn_b,
            const float* __restrict__ e1g,     const float* __restrict__ e1b,
            const float* __restrict__ c1w,     const float* __restrict__ c1b,
            const float* __restrict__ e2g,     const float* __restrict__ e2b,
            const float* __restrict__ c2w,     const float* __restrict__ c2b,
            float* __restrict__ out, float* __restrict__ ws)
{
  __shared__ float s_red[BS*32];
  __shared__ float s_p2[BS];
  __shared__ float s_bcA[128];
  __shared__ float s_bcB[128];

  const int t   = threadIdx.x;
  const int p   = blockIdx.x * BS + t;         // position in [0,65536)
  const int rep = blockIdx.x & 7;
  unsigned* cnt = (unsigned*)ws;
  float* stats  = ws + STATS_F;
  float* w2t    = ws + W2T_F;
  float* zg     = out;                         // lower 32MB of out = z scratch (own column only)
  unsigned tgt  = 0;

  const int bb = p >> 13, ll = p & 8191;
  const int pbase = bb * (256*8192) + ll;

  // transpose end_conv2_w (256x256) -> w2t[k][o]; agent-scope stores for cross-XCD visibility
  {
    int o = p & 255, kk = p >> 8;
    __hip_atomic_store(&w2t[kk*256 + o], c2w[o*256 + kk],
                       __ATOMIC_RELAXED, __HIP_MEMORY_SCOPE_AGENT);
  }

  // ---- start conv: x[32] = start_w(32x256) @ xin + start_b
  float x[32];
  #pragma unroll
  for (int j = 0; j < 32; ++j) x[j] = start_b[j];
  #pragma clang loop unroll(disable)
  for (int c8 = 0; c8 < 32; ++c8) {
    float xv[8];
    #pragma unroll
    for (int cc = 0; cc < 8; ++cc) xv[cc] = xin[pbase + (c8*8+cc)*8192];
    #pragma unroll
    for (int j = 0; j < 32; ++j)
      #pragma unroll
      for (int cc = 0; cc < 8; ++cc)
        x[j] = fmaf(start_w[j*256 + c8*8 + cc], xv[cc], x[j]);
  }

  // ---- 40 residual layers (dilate is a pure position permutation -> value no-op)
  #pragma clang loop unroll(disable)
  for (int i = 0; i < 40; ++i) {
    float g[16];
    #pragma unroll
    for (int j = 0; j < 16; ++j) g[j] = gate_b[i*16 + j];
    #pragma unroll
    for (int j = 0; j < 16; ++j)
      #pragma unroll
      for (int k = 0; k < 32; ++k)
        g[j] = fmaf(gate_w[i*512 + j*32 + k], x[k], g[j]);

    float cm[32];
    #pragma unroll
    for (int j = 0; j < 16; ++j) mish2(g[j], cm[j], cm[j+16]);

    float r[32];
    #pragma unroll
    for (int j = 0; j < 32; ++j) r[j] = res_b[i*32 + j];
    #pragma unroll
    for (int j = 0; j < 32; ++j)
      #pragma unroll
      for (int k = 0; k < 32; ++k)
        r[j] = fmaf(res_w[i*1024 + j*32 + k], cm[k], r[j]);

    block_reduce_stats(r, s_red, s_p2, stats + i*512, t, rep);
    tgt += NBLK; grid_sync(cnt, tgt);

    if (t < 32) {
      float S = 0.f, Q = 0.f;
      #pragma unroll
      for (int r2 = 0; r2 < 8; ++r2) {
        S += stats[i*512 + r2*64 + t];
        Q += stats[i*512 + r2*64 + 32 + t];
      }
      float mean = S * (1.f/65536.f);
      float var  = fmaf(-mean, mean, Q * (1.f/65536.f));
      float sc   = bn_g[i*32+t] * rsqrtf(var + 1e-5f);
      s_bcA[t] = sc;
      s_bcB[t] = fmaf(-mean, sc, bn_b[i*32+t]);
    }
    __syncthreads();
    #pragma unroll
    for (int c = 0; c < 32; ++c)
      x[c] += fmaf(r[c], s_bcA[c], s_bcB[c]);
  }

  // ---- end: BN1 -> concat_mish (64)
  block_reduce_stats(x, s_red, s_p2, stats + 40*512, t, rep);
  tgt += NBLK; grid_sync(cnt, tgt);
  if (t < 32) {
    float S = 0.f, Q = 0.f;
    #pragma unroll
    for (int r2 = 0; r2 < 8; ++r2) {
      S += stats[40*512 + r2*64 + t];
      Q += stats[40*512 + r2*64 + 32 + t];
    }
    float mean = S * (1.f/65536.f);
    float var  = fmaf(-mean, mean, Q * (1.f/65536.f));
    float sc   = e1g[t] * rsqrtf(var + 1e-5f);
    s_bcA[t] = sc;
    s_bcB[t] = fmaf(-mean, sc, e1b[t]);
  }
  __syncthreads();
  float mp[32], mn[32];
  #pragma unroll
  for (int c = 0; c < 32; ++c) {
    float xh = fmaf(x[c], s_bcA[c], s_bcB[c]);
    mish2(xh, mp[c], mn[c]);
  }

  // ---- conv1 (128x64) in 4 passes of 32 out-ch; z -> zg (own column) + stats
  #pragma clang loop unroll(disable)
  for (int pp = 0; pp < 4; ++pp) {
    float zc[32];
    #pragma unroll
    for (int j = 0; j < 32; ++j) zc[j] = c1b[pp*32 + j];
    #pragma unroll
    for (int j = 0; j < 32; ++j)
      #pragma unroll
      for (int k = 0; k < 32; ++k) {
        zc[j] = fmaf(c1w[(pp*32+j)*64 + k],      mp[k], zc[j]);
        zc[j] = fmaf(c1w[(pp*32+j)*64 + 32 + k], mn[k], zc[j]);
      }
    #pragma unroll
    for (int j = 0; j < 32; ++j) zg[(pp*32+j)*65536 + p] = zc[j];
    block_reduce_stats(zc, s_red, s_p2, stats + (41+pp)*512, t, rep);
  }
  tgt += NBLK; grid_sync(cnt, tgt);

  if (t < 128) {
    int slot = 41 + (t >> 5), c = t & 31;
    float S = 0.f, Q = 0.f;
    #pragma unroll
    for (int r2 = 0; r2 < 8; ++r2) {
      S += stats[slot*512 + r2*64 + c];
      Q += stats[slot*512 + r2*64 + 32 + c];
    }
    float mean = S * (1.f/65536.f);
    float var  = fmaf(-mean, mean, Q * (1.f/65536.f));
    float sc   = e2g[t] * rsqrtf(var + 1e-5f);
    s_bcA[t] = sc;
    s_bcB[t] = fmaf(-mean, sc, e2b[t]);
  }
  __syncthreads();

  // ---- conv2 (256x256): acc over all 256 outputs, k dynamic
  float acc[256];
  #pragma unroll
  for (int o = 0; o < 256; ++o) acc[o] = c2b[o];
  #pragma clang loop unroll(disable)
  for (int k = 0; k < 128; ++k) {
    float zv = zg[k*65536 + p];
    float zh = fmaf(zv, s_bcA[k], s_bcB[k]);
    float mpv, mnv; mish2(zh, mpv, mnv);
    const float* w0 = &w2t[k*256];
    const float* w1 = &w2t[(k+128)*256];
    #pragma unroll
    for (int o = 0; o < 256; ++o)
      acc[o] = fmaf(w0[o], mpv, fmaf(w1[o], mnv, acc[o]));
  }

  // all zg reads complete device-wide before any out write (zg aliases out)
  tgt += NBLK; grid_sync(cnt, tgt);

  #pragma unroll
  for (int o = 0; o < 256; ++o)
    out[bb*(256*8192) + o*8192 + ll] = acc[o];
}

extern "C" void kernel_launch(void* const* d_in, const int* in_sizes, int n_in,
                              void* d_out, int out_size, void* d_ws, size_t ws_size,
                              hipStream_t stream) {
  // zero barrier counter + stats slots (45*8*64 floats): (256 + 23040)*4 bytes
  hipMemsetAsync(d_ws, 0, (STATS_F + 45*512) * 4, stream);

  const float* xin = (const float*)d_in[0];
  const float* sw  = (const float*)d_in[1];
  const float* sb  = (const float*)d_in[2];
  const float* gw  = (const float*)d_in[3];
  const float* gb  = (const float*)d_in[4];
  const float* rw  = (const float*)d_in[5];
  const float* rb  = (const float*)d_in[6];
  const float* bng = (const float*)d_in[7];
  const float* bnb = (const float*)d_in[8];
  const float* e1g = (const float*)d_in[9];
  const float* e1b = (const float*)d_in[10];
  const float* c1w = (const float*)d_in[11];
  const float* c1b = (const float*)d_in[12];
  const float* e2g = (const float*)d_in[13];
  const float* e2b = (const float*)d_in[14];
  const float* c2w = (const float*)d_in[15];
  const float* c2b = (const float*)d_in[16];
  float* out = (float*)d_out;
  float* ws  = (float*)d_ws;

  void* args[] = { &xin, &sw, &sb, &gw, &gb, &rw, &rb, &bng, &bnb,
                   &e1g, &e1b, &c1w, &c1b, &e2g, &e2b, &c2w, &c2b, &out, &ws };
  hipError_t err = hipLaunchCooperativeKernel((const void*)qnet_kernel,
                                              dim3(NBLK), dim3(BS), args, 0, stream);
  if (err != hipSuccess) {
    // fallback: plain launch (manual barrier still correct; 256 blocks <= 256 CUs co-resident)
    hipLaunchKernelGGL(qnet_kernel, dim3(NBLK), dim3(BS), 0, stream,
                       xin, sw, sb, gw, gb, rw, rb, bng, bnb,
                       e1g, e1b, c1w, c1b, e2g, e2b, c2w, c2b, out, ws);
  }
}

// Round 2
// 2613.875 us; speedup vs baseline: 1.0784x; 1.0784x over previous
//
#include <hip/hip_runtime.h>

#define NBLK 256
#define BS   256
// ws layout (floats): [0..255] counter+pad, [256 .. 256+45*512) stats (45 slots x 8 reps x 64),
// [23296 .. 23296+65536) transposed end_conv2_w
#define STATS_F 256
#define W2T_F   23296

__device__ __forceinline__ void mish2(float v, float& mp, float& mn) {
  // mish(v) = v*tanh(softplus(v)) = v*(u^2+2u)/(u^2+2u+2), u=e^v
  // mish(-v) = -v*(2u+1)/(2u^2+2u+1)   (shares u)
  float vc = fminf(fmaxf(v, -30.f), 30.f);
  float u  = __expf(vc);
  float n1 = u * (u + 2.f);
  mp = v * n1 * __builtin_amdgcn_rcpf(n1 + 2.f);
  float n2 = fmaf(2.f, u, 1.f);
  float d2 = fmaf(2.f * u, u, n2);
  mn = -v * n2 * __builtin_amdgcn_rcpf(d2);
}

// Fence-free grid barrier. Valid because ALL cross-block data flows through
// device-scope atomics (stats adds, counter RMW) which execute at the device
// coherent point, and __syncthreads' compiler-emitted s_waitcnt vmcnt(0)
// guarantees each wave's atomics completed before its block signals arrival.
// No __threadfence: avoids per-block L2 writeback + flash-invalidate (the
// R0 stall: ~256 blocks x 43 barriers of whole-L2 inv).
__device__ __forceinline__ void grid_sync(unsigned* cnt, unsigned target) {
  __syncthreads();               // vmcnt(0) before s_barrier: prior atomics complete
  if (threadIdx.x == 0) {
    __hip_atomic_fetch_add(cnt, 1u, __ATOMIC_RELAXED, __HIP_MEMORY_SCOPE_AGENT);
    while (__hip_atomic_load(cnt, __ATOMIC_RELAXED, __HIP_MEMORY_SCOPE_AGENT) < target)
      __builtin_amdgcn_s_sleep(1);
  }
  __syncthreads();
}

// cache-bypassing (agent-scope) load: stats were written by device-scope
// atomics at the coherent point; bypass L1/L2 to read them safely.
__device__ __forceinline__ float coherent_ld(const float* p) {
  return __hip_atomic_load(p, __ATOMIC_RELAXED, __HIP_MEMORY_SCOPE_AGENT);
}

// Per-block reduce of 32 per-thread values -> 64 quantities (32 sums + 32 sumsq),
// atomically added into slot[rep*64 + q]. s_red is BS*32 floats, xor-swizzled.
__device__ __forceinline__ void block_reduce_stats(const float (&vals)[32],
    float* s_red, float* s_p2, float* slot, int t, int rep) {
  #pragma unroll
  for (int cc = 0; cc < 8; ++cc) {
    float4 v = make_float4(vals[cc*4+0], vals[cc*4+1], vals[cc*4+2], vals[cc*4+3]);
    *(float4*)(&s_red[t*32 + ((cc ^ (t & 7)) << 2)]) = v;  // conflict-free (2-way)
  }
  __syncthreads();
  {
    int q = t & 63, grp = t >> 6, c = q & 31;
    bool issq = (q >= 32);
    float acc = 0.f;
    #pragma clang loop unroll_count(8)
    for (int rr = 0; rr < 64; ++rr) {
      int row = grp * 64 + rr;
      float v = s_red[row*32 + ((((c >> 2) ^ (row & 7)) << 2) | (c & 3))];
      acc = fmaf(v, issq ? v : 1.f, acc);
    }
    s_p2[t] = acc;   // t == grp*64+q
  }
  __syncthreads();
  if (t < 64) {
    float tot = s_p2[t] + s_p2[t+64] + s_p2[t+128] + s_p2[t+192];
    unsafeAtomicAdd(&slot[rep*64 + t], tot);
  }
}

extern "C" __global__ void __launch_bounds__(BS, 1)
qnet_kernel(const float* __restrict__ xin,
            const float* __restrict__ start_w, const float* __restrict__ start_b,
            const float* __restrict__ gate_w,  const float* __restrict__ gate_b,
            const float* __restrict__ res_w,   const float* __restrict__ res_b,
            const float* __restrict__ bn_g,    const float* __restrict__ bn_b,
            const float* __restrict__ e1g,     const float* __restrict__ e1b,
            const float* __restrict__ c1w,     const float* __restrict__ c1b,
            const float* __restrict__ e2g,     const float* __restrict__ e2b,
            const float* __restrict__ c2w,     const float* __restrict__ c2b,
            float* __restrict__ out, float* __restrict__ ws)
{
  __shared__ float s_red[BS*32];
  __shared__ float s_p2[BS];
  __shared__ float s_bcA[128];
  __shared__ float s_bcB[128];

  const int t   = threadIdx.x;
  const int p   = blockIdx.x * BS + t;         // position in [0,65536)
  const int rep = blockIdx.x & 7;
  unsigned* cnt = (unsigned*)ws;
  float* stats  = ws + STATS_F;
  float* w2t    = ws + W2T_F;
  float* zg     = out;                         // lower 32MB of out = z scratch (own column only)
  unsigned tgt  = 0;

  const int bb = p >> 13, ll = p & 8191;
  const int pbase = bb * (256*8192) + ll;

  // transpose end_conv2_w (256x256) -> w2t[k][o]; agent-scope stores for cross-XCD visibility
  {
    int o = p & 255, kk = p >> 8;
    __hip_atomic_store(&w2t[kk*256 + o], c2w[o*256 + kk],
                       __ATOMIC_RELAXED, __HIP_MEMORY_SCOPE_AGENT);
  }

  // ---- start conv: x[32] = start_w(32x256) @ xin + start_b
  float x[32];
  #pragma unroll
  for (int j = 0; j < 32; ++j) x[j] = start_b[j];
  #pragma clang loop unroll(disable)
  for (int c8 = 0; c8 < 32; ++c8) {
    float xv[8];
    #pragma unroll
    for (int cc = 0; cc < 8; ++cc) xv[cc] = xin[pbase + (c8*8+cc)*8192];
    #pragma unroll
    for (int j = 0; j < 32; ++j)
      #pragma unroll
      for (int cc = 0; cc < 8; ++cc)
        x[j] = fmaf(start_w[j*256 + c8*8 + cc], xv[cc], x[j]);
  }

  // ---- 40 residual layers (dilate is a pure position permutation -> value no-op)
  #pragma clang loop unroll(disable)
  for (int i = 0; i < 40; ++i) {
    float g[16];
    #pragma unroll
    for (int j = 0; j < 16; ++j) g[j] = gate_b[i*16 + j];
    #pragma unroll
    for (int j = 0; j < 16; ++j)
      #pragma unroll
      for (int k = 0; k < 32; ++k)
        g[j] = fmaf(gate_w[i*512 + j*32 + k], x[k], g[j]);

    float cm[32];
    #pragma unroll
    for (int j = 0; j < 16; ++j) mish2(g[j], cm[j], cm[j+16]);

    float r[32];
    #pragma unroll
    for (int j = 0; j < 32; ++j) r[j] = res_b[i*32 + j];
    #pragma unroll
    for (int j = 0; j < 32; ++j)
      #pragma unroll
      for (int k = 0; k < 32; ++k)
        r[j] = fmaf(res_w[i*1024 + j*32 + k], cm[k], r[j]);

    block_reduce_stats(r, s_red, s_p2, stats + i*512, t, rep);
    tgt += NBLK; grid_sync(cnt, tgt);

    if (t < 32) {
      float S = 0.f, Q = 0.f;
      #pragma unroll
      for (int r2 = 0; r2 < 8; ++r2) {
        S += coherent_ld(&stats[i*512 + r2*64 + t]);
        Q += coherent_ld(&stats[i*512 + r2*64 + 32 + t]);
      }
      float mean = S * (1.f/65536.f);
      float var  = fmaf(-mean, mean, Q * (1.f/65536.f));
      float sc   = bn_g[i*32+t] * rsqrtf(var + 1e-5f);
      s_bcA[t] = sc;
      s_bcB[t] = fmaf(-mean, sc, bn_b[i*32+t]);
    }
    __syncthreads();
    #pragma unroll
    for (int c = 0; c < 32; ++c)
      x[c] += fmaf(r[c], s_bcA[c], s_bcB[c]);
  }

  // ---- end: BN1 -> concat_mish (64)
  block_reduce_stats(x, s_red, s_p2, stats + 40*512, t, rep);
  tgt += NBLK; grid_sync(cnt, tgt);
  if (t < 32) {
    float S = 0.f, Q = 0.f;
    #pragma unroll
    for (int r2 = 0; r2 < 8; ++r2) {
      S += coherent_ld(&stats[40*512 + r2*64 + t]);
      Q += coherent_ld(&stats[40*512 + r2*64 + 32 + t]);
    }
    float mean = S * (1.f/65536.f);
    float var  = fmaf(-mean, mean, Q * (1.f/65536.f));
    float sc   = e1g[t] * rsqrtf(var + 1e-5f);
    s_bcA[t] = sc;
    s_bcB[t] = fmaf(-mean, sc, e1b[t]);
  }
  __syncthreads();
  float mp[32], mn[32];
  #pragma unroll
  for (int c = 0; c < 32; ++c) {
    float xh = fmaf(x[c], s_bcA[c], s_bcB[c]);
    mish2(xh, mp[c], mn[c]);
  }

  // ---- conv1 (128x64) in 4 passes of 32 out-ch; z -> zg (own column) + stats
  #pragma clang loop unroll(disable)
  for (int pp = 0; pp < 4; ++pp) {
    float zc[32];
    #pragma unroll
    for (int j = 0; j < 32; ++j) zc[j] = c1b[pp*32 + j];
    #pragma unroll
    for (int j = 0; j < 32; ++j)
      #pragma unroll
      for (int k = 0; k < 32; ++k) {
        zc[j] = fmaf(c1w[(pp*32+j)*64 + k],      mp[k], zc[j]);
        zc[j] = fmaf(c1w[(pp*32+j)*64 + 32 + k], mn[k], zc[j]);
      }
    #pragma unroll
    for (int j = 0; j < 32; ++j) zg[(pp*32+j)*65536 + p] = zc[j];
    block_reduce_stats(zc, s_red, s_p2, stats + (41+pp)*512, t, rep);
  }
  tgt += NBLK; grid_sync(cnt, tgt);

  if (t < 128) {
    int slot = 41 + (t >> 5), c = t & 31;
    float S = 0.f, Q = 0.f;
    #pragma unroll
    for (int r2 = 0; r2 < 8; ++r2) {
      S += coherent_ld(&stats[slot*512 + r2*64 + c]);
      Q += coherent_ld(&stats[slot*512 + r2*64 + 32 + c]);
    }
    float mean = S * (1.f/65536.f);
    float var  = fmaf(-mean, mean, Q * (1.f/65536.f));
    float sc   = e2g[t] * rsqrtf(var + 1e-5f);
    s_bcA[t] = sc;
    s_bcB[t] = fmaf(-mean, sc, e2b[t]);
  }
  __syncthreads();

  // ---- conv2 (256x256): acc over all 256 outputs, k dynamic
  float acc[256];
  #pragma unroll
  for (int o = 0; o < 256; ++o) acc[o] = c2b[o];
  #pragma clang loop unroll(disable)
  for (int k = 0; k < 128; ++k) {
    float zv = zg[k*65536 + p];
    float zh = fmaf(zv, s_bcA[k], s_bcB[k]);
    float mpv, mnv; mish2(zh, mpv, mnv);
    const float* w0 = &w2t[k*256];
    const float* w1 = &w2t[(k+128)*256];
    #pragma unroll
    for (int o = 0; o < 256; ++o)
      acc[o] = fmaf(w0[o], mpv, fmaf(w1[o], mnv, acc[o]));
  }

  // all zg reads complete device-wide before any out write (zg aliases out)
  tgt += NBLK; grid_sync(cnt, tgt);

  #pragma unroll
  for (int o = 0; o < 256; ++o)
    out[bb*(256*8192) + o*8192 + ll] = acc[o];
}

extern "C" void kernel_launch(void* const* d_in, const int* in_sizes, int n_in,
                              void* d_out, int out_size, void* d_ws, size_t ws_size,
                              hipStream_t stream) {
  // zero barrier counter + stats slots (45*8*64 floats): (256 + 23040)*4 bytes
  hipMemsetAsync(d_ws, 0, (STATS_F + 45*512) * 4, stream);

  const float* xin = (const float*)d_in[0];
  const float* sw  = (const float*)d_in[1];
  const float* sb  = (const float*)d_in[2];
  const float* gw  = (const float*)d_in[3];
  const float* gb  = (const float*)d_in[4];
  const float* rw  = (const float*)d_in[5];
  const float* rb  = (const float*)d_in[6];
  const float* bng = (const float*)d_in[7];
  const float* bnb = (const float*)d_in[8];
  const float* e1g = (const float*)d_in[9];
  const float* e1b = (const float*)d_in[10];
  const float* c1w = (const float*)d_in[11];
  const float* c1b = (const float*)d_in[12];
  const float* e2g = (const float*)d_in[13];
  const float* e2b = (const float*)d_in[14];
  const float* c2w = (const float*)d_in[15];
  const float* c2b = (const float*)d_in[16];
  float* out = (float*)d_out;
  float* ws  = (float*)d_ws;

  void* args[] = { &xin, &sw, &sb, &gw, &gb, &rw, &rb, &bng, &bnb,
                   &e1g, &e1b, &c1w, &c1b, &e2g, &e2b, &c2w, &c2b, &out, &ws };
  hipError_t err = hipLaunchCooperativeKernel((const void*)qnet_kernel,
                                              dim3(NBLK), dim3(BS), args, 0, stream);
  if (err != hipSuccess) {
    // fallback: plain launch (manual barrier still correct; 256 blocks <= 256 CUs co-resident)
    hipLaunchKernelGGL(qnet_kernel, dim3(NBLK), dim3(BS), 0, stream,
                       xin, sw, sb, gw, gb, rw, rb, bng, bnb,
                       e1g, e1b, c1w, c1b, e2g, e2b, c2w, c2b, out, ws);
  }
}

// Round 3
// 2606.089 us; speedup vs baseline: 1.0816x; 1.0030x over previous
//
#include <hip/hip_runtime.h>

#define NBLK 256
#define BS   256
// ws layout (floats): [0]=gen flag (line 0), [16..144) = 8 arrival counters (one per line),
// [256 .. 256+65536) transposed end_conv2_w. Stats live in the upper half of `out`.
#define W2T_F   256
#define STATS_OUT_OFF (8u*1024u*1024u)   // floats; out[0..8M)=zg scratch, stats at out[8M..)
#define SLOT_STRIDE 16384                 // 256 blocks x 64 q

__device__ __forceinline__ void mish2(float v, float& mp, float& mn) {
  // mish(v) = v*tanh(softplus(v)) = v*(u^2+2u)/(u^2+2u+2), u=e^v
  // mish(-v) = -v*(2u+1)/(2u^2+2u+1)   (shares u)
  float vc = fminf(fmaxf(v, -30.f), 30.f);
  float u  = __expf(vc);
  float n1 = u * (u + 2.f);
  mp = v * n1 * __builtin_amdgcn_rcpf(n1 + 2.f);
  float n2 = fmaf(2.f, u, 1.f);
  float d2 = fmaf(2.f * u, u, n2);
  mn = -v * n2 * __builtin_amdgcn_rcpf(d2);
}

__device__ __forceinline__ float coherent_ld(const float* p) {
  return __hip_atomic_load(p, __ATOMIC_RELAXED, __HIP_MEMORY_SCOPE_AGENT);
}
__device__ __forceinline__ void coherent_st(float* p, float v) {
  __hip_atomic_store(p, v, __ATOMIC_RELAXED, __HIP_MEMORY_SCOPE_AGENT);
}

// Low-contention grid barrier: arrivals spread over 8 counter lines (32 RMW each);
// block 0 aggregates and publishes generation on a SEPARATE read-only flag line.
// Pollers never touch the RMW lines -> no LLC bank saturation (the R1 60us/barrier stall).
__device__ __forceinline__ void grid_sync(float* ws, unsigned gen, bool flush) {
  __syncthreads();                       // all waves vmcnt(0): stats stores complete
  if (threadIdx.x == 0) {
    if (flush) __threadfence();          // once, at final barrier: wbl2 drains dirty zg lines
    unsigned* flag = (unsigned*)ws;                  // line 0
    unsigned* cnts = (unsigned*)ws + 16;             // 8 lines, stride 16 dwords
    __hip_atomic_fetch_add(&cnts[(blockIdx.x & 7) * 16], 1u,
        __ATOMIC_RELAXED, __HIP_MEMORY_SCOPE_AGENT);
    if (blockIdx.x == 0) {
      unsigned sum;
      do {
        __builtin_amdgcn_s_sleep(1);
        sum = 0;
        #pragma unroll
        for (int x = 0; x < 8; ++x)
          sum += __hip_atomic_load(&cnts[x*16], __ATOMIC_RELAXED, __HIP_MEMORY_SCOPE_AGENT);
      } while (sum < gen * NBLK);
      __hip_atomic_store(flag, gen, __ATOMIC_RELAXED, __HIP_MEMORY_SCOPE_AGENT);
    } else {
      while (__hip_atomic_load(flag, __ATOMIC_RELAXED, __HIP_MEMORY_SCOPE_AGENT) < gen)
        __builtin_amdgcn_s_sleep(2);
    }
  }
  __syncthreads();
}

// Per-block reduce of 32 per-thread values -> 64 partials (32 sums + 32 sumsq),
// stored contention-free to this block's private stats row (agent-scope, coalesced).
__device__ __forceinline__ void block_reduce_stats(const float (&vals)[32],
    float* s_red, float* s_p2, float* slot, int t) {
  #pragma unroll
  for (int cc = 0; cc < 8; ++cc) {
    float4 v = make_float4(vals[cc*4+0], vals[cc*4+1], vals[cc*4+2], vals[cc*4+3]);
    *(float4*)(&s_red[t*32 + ((cc ^ (t & 7)) << 2)]) = v;  // xor-swizzle: conflict-free
  }
  __syncthreads();
  {
    int q = t & 63, grp = t >> 6, c = q & 31;
    bool issq = (q >= 32);
    float acc = 0.f;
    #pragma clang loop unroll_count(8)
    for (int rr = 0; rr < 64; ++rr) {
      int row = grp * 64 + rr;
      float v = s_red[row*32 + ((((c >> 2) ^ (row & 7)) << 2) | (c & 3))];
      acc = fmaf(v, issq ? v : 1.f, acc);
    }
    s_p2[t] = acc;   // t == grp*64+q
  }
  __syncthreads();
  if (t < 64) {
    float tot = s_p2[t] + s_p2[t+64] + s_p2[t+128] + s_p2[t+192];
    coherent_st(&slot[blockIdx.x * 64 + t], tot);   // zero-contention store
  }
  __syncthreads();   // s_p2 reused by read-back
}

// Sum this slot's 256 per-block partials: lane q (t<64) sums its strided column.
// Wave-coalesced (4 lines per step), ~32 loads in flight.
__device__ __forceinline__ float slot_col_sum(const float* sg, int slot, int q) {
  const float* col = sg + (size_t)slot * SLOT_STRIDE + q;
  float tot = 0.f;
  #pragma clang loop unroll_count(32)
  for (int b2 = 0; b2 < 256; ++b2) tot += coherent_ld(&col[b2*64]);
  return tot;
}

extern "C" __global__ void __launch_bounds__(BS, 1)
qnet_kernel(const float* __restrict__ xin,
            const float* __restrict__ start_w, const float* __restrict__ start_b,
            const float* __restrict__ gate_w,  const float* __restrict__ gate_b,
            const float* __restrict__ res_w,   const float* __restrict__ res_b,
            const float* __restrict__ bn_g,    const float* __restrict__ bn_b,
            const float* __restrict__ e1g,     const float* __restrict__ e1b,
            const float* __restrict__ c1w,     const float* __restrict__ c1b,
            const float* __restrict__ e2g,     const float* __restrict__ e2b,
            const float* __restrict__ c2w,     const float* __restrict__ c2b,
            float* __restrict__ out, float* __restrict__ ws)
{
  __shared__ float s_red[BS*32];
  __shared__ float s_p2[BS];
  __shared__ float s_bcA[128];
  __shared__ float s_bcB[128];

  const int t   = threadIdx.x;
  const int p   = blockIdx.x * BS + t;         // position in [0,65536)
  float* w2t    = ws + W2T_F;
  float* zg     = out;                         // lower 32MB of out = z scratch (own column only)
  float* sg     = out + STATS_OUT_OFF;         // stats region (overwritten only after final barrier)
  unsigned gen  = 0;

  const int bb = p >> 13, ll = p & 8191;
  const int pbase = bb * (256*8192) + ll;

  // transpose end_conv2_w (256x256) -> w2t[k][o]; agent-scope stores (cross-XCD via LLC)
  {
    int o = p & 255, kk = p >> 8;
    coherent_st(&w2t[kk*256 + o], c2w[o*256 + kk]);
  }

  // ---- start conv: x[32] = start_w(32x256) @ xin + start_b
  float x[32];
  #pragma unroll
  for (int j = 0; j < 32; ++j) x[j] = start_b[j];
  #pragma clang loop unroll(disable)
  for (int c8 = 0; c8 < 32; ++c8) {
    float xv[8];
    #pragma unroll
    for (int cc = 0; cc < 8; ++cc) xv[cc] = xin[pbase + (c8*8+cc)*8192];
    #pragma unroll
    for (int j = 0; j < 32; ++j)
      #pragma unroll
      for (int cc = 0; cc < 8; ++cc)
        x[j] = fmaf(start_w[j*256 + c8*8 + cc], xv[cc], x[j]);
  }

  // ---- 40 residual layers (dilate is a pure position permutation -> value no-op)
  #pragma clang loop unroll(disable)
  for (int i = 0; i < 40; ++i) {
    float g[16];
    #pragma unroll
    for (int j = 0; j < 16; ++j) g[j] = gate_b[i*16 + j];
    #pragma unroll
    for (int j = 0; j < 16; ++j)
      #pragma unroll
      for (int k = 0; k < 32; ++k)
        g[j] = fmaf(gate_w[i*512 + j*32 + k], x[k], g[j]);

    float cm[32];
    #pragma unroll
    for (int j = 0; j < 16; ++j) mish2(g[j], cm[j], cm[j+16]);

    float r[32];
    #pragma unroll
    for (int j = 0; j < 32; ++j) r[j] = res_b[i*32 + j];
    #pragma unroll
    for (int j = 0; j < 32; ++j)
      #pragma unroll
      for (int k = 0; k < 32; ++k)
        r[j] = fmaf(res_w[i*1024 + j*32 + k], cm[k], r[j]);

    block_reduce_stats(r, s_red, s_p2, sg + (size_t)i * SLOT_STRIDE, t);
    ++gen; grid_sync(ws, gen, false);

    if (t < 64) s_p2[t] = slot_col_sum(sg, i, t);
    __syncthreads();
    if (t < 32) {
      float mean = s_p2[t] * (1.f/65536.f);
      float var  = fmaf(-mean, mean, s_p2[t+32] * (1.f/65536.f));
      float sc   = bn_g[i*32+t] * rsqrtf(var + 1e-5f);
      s_bcA[t] = sc;
      s_bcB[t] = fmaf(-mean, sc, bn_b[i*32+t]);
    }
    __syncthreads();
    #pragma unroll
    for (int c = 0; c < 32; ++c)
      x[c] += fmaf(r[c], s_bcA[c], s_bcB[c]);
  }

  // ---- end: BN1 -> concat_mish (64)
  block_reduce_stats(x, s_red, s_p2, sg + 40 * SLOT_STRIDE, t);
  ++gen; grid_sync(ws, gen, false);
  if (t < 64) s_p2[t] = slot_col_sum(sg, 40, t);
  __syncthreads();
  if (t < 32) {
    float mean = s_p2[t] * (1.f/65536.f);
    float var  = fmaf(-mean, mean, s_p2[t+32] * (1.f/65536.f));
    float sc   = e1g[t] * rsqrtf(var + 1e-5f);
    s_bcA[t] = sc;
    s_bcB[t] = fmaf(-mean, sc, e1b[t]);
  }
  __syncthreads();
  float mp[32], mn[32];
  #pragma unroll
  for (int c = 0; c < 32; ++c) {
    float xh = fmaf(x[c], s_bcA[c], s_bcB[c]);
    mish2(xh, mp[c], mn[c]);
  }

  // ---- conv1 (128x64) in 4 passes of 32 out-ch; z -> zg (own column) + stats
  #pragma clang loop unroll(disable)
  for (int pp = 0; pp < 4; ++pp) {
    float zc[32];
    #pragma unroll
    for (int j = 0; j < 32; ++j) zc[j] = c1b[pp*32 + j];
    #pragma unroll
    for (int j = 0; j < 32; ++j)
      #pragma unroll
      for (int k = 0; k < 32; ++k) {
        zc[j] = fmaf(c1w[(pp*32+j)*64 + k],      mp[k], zc[j]);
        zc[j] = fmaf(c1w[(pp*32+j)*64 + 32 + k], mn[k], zc[j]);
      }
    #pragma unroll
    for (int j = 0; j < 32; ++j) zg[(pp*32+j)*65536 + p] = zc[j];
    block_reduce_stats(zc, s_red, s_p2, sg + (size_t)(41+pp) * SLOT_STRIDE, t);
  }
  ++gen; grid_sync(ws, gen, false);

  // e2 read-back: all 4 waves, wave w handles slot 41+w, lane q its column
  {
    int slot = 41 + (t >> 6), q = t & 63;
    s_p2[t] = slot_col_sum(sg, slot, q);
  }
  __syncthreads();
  if (t < 128) {
    float S = s_p2[((t>>5)<<6) | (t&31)];
    float Q = s_p2[((t>>5)<<6) | 32 | (t&31)];
    float mean = S * (1.f/65536.f);
    float var  = fmaf(-mean, mean, Q * (1.f/65536.f));
    float sc   = e2g[t] * rsqrtf(var + 1e-5f);
    s_bcA[t] = sc;
    s_bcB[t] = fmaf(-mean, sc, e2b[t]);
  }
  __syncthreads();

  // ---- conv2 (256x256): acc over all 256 outputs, k dynamic, zv software-prefetched
  float acc[256];
  #pragma unroll
  for (int o = 0; o < 256; ++o) acc[o] = c2b[o];
  float zv_next = zg[p];
  #pragma clang loop unroll(disable)
  for (int k = 0; k < 128; ++k) {
    float zv = zv_next;
    zv_next = zg[((k+1)&127)*65536 + p];
    float zh = fmaf(zv, s_bcA[k], s_bcB[k]);
    float mpv, mnv; mish2(zh, mpv, mnv);
    const float* w0 = &w2t[k*256];
    const float* w1 = &w2t[(k+128)*256];
    #pragma unroll
    for (int o = 0; o < 256; ++o)
      acc[o] = fmaf(w0[o], mpv, fmaf(w1[o], mnv, acc[o]));
  }

  // final barrier WITH flush: wbl2 drains dirty zg lines from every XCD's L2 so the
  // plain final writes below are the only dirty copies (fixes zg/out aliasing race)
  ++gen; grid_sync(ws, gen, true);

  #pragma unroll
  for (int o = 0; o < 256; ++o)
    out[bb*(256*8192) + o*8192 + ll] = acc[o];
}

extern "C" void kernel_launch(void* const* d_in, const int* in_sizes, int n_in,
                              void* d_out, int out_size, void* d_ws, size_t ws_size,
                              hipStream_t stream) {
  // zero barrier flag + arrival counters (first 1 KB of ws)
  hipMemsetAsync(d_ws, 0, 1024, stream);

  const float* xin = (const float*)d_in[0];
  const float* sw  = (const float*)d_in[1];
  const float* sb  = (const float*)d_in[2];
  const float* gw  = (const float*)d_in[3];
  const float* gb  = (const float*)d_in[4];
  const float* rw  = (const float*)d_in[5];
  const float* rb  = (const float*)d_in[6];
  const float* bng = (const float*)d_in[7];
  const float* bnb = (const float*)d_in[8];
  const float* e1g = (const float*)d_in[9];
  const float* e1b = (const float*)d_in[10];
  const float* c1w = (const float*)d_in[11];
  const float* c1b = (const float*)d_in[12];
  const float* e2g = (const float*)d_in[13];
  const float* e2b = (const float*)d_in[14];
  const float* c2w = (const float*)d_in[15];
  const float* c2b = (const float*)d_in[16];
  float* out = (float*)d_out;
  float* ws  = (float*)d_ws;

  void* args[] = { &xin, &sw, &sb, &gw, &gb, &rw, &rb, &bng, &bnb,
                   &e1g, &e1b, &c1w, &c1b, &e2g, &e2b, &c2w, &c2b, &out, &ws };
  hipError_t err = hipLaunchCooperativeKernel((const void*)qnet_kernel,
                                              dim3(NBLK), dim3(BS), args, 0, stream);
  if (err != hipSuccess) {
    // fallback: plain launch (manual barrier still correct; 256 blocks <= 256 CUs co-resident)
    hipLaunchKernelGGL(qnet_kernel, dim3(NBLK), dim3(BS), 0, stream,
                       xin, sw, sb, gw, gb, rw, rb, bng, bnb,
                       e1g, e1b, c1w, c1b, e2g, e2b, c2w, c2b, out, ws);
  }
}

// Round 4
// 2493.715 us; speedup vs baseline: 1.1303x; 1.0451x over previous
//
#include <hip/hip_runtime.h>

#define NBLK 256
#define BS   256
// ws layout (dwords): [0 .. 4096) = 256 per-block flag lines (stride 16 dw = 64B);
// [4096 .. 4608) = 32 arrival counter lines (stride 16 dw);
// floats from W2T_F: transposed end_conv2_w (65536). Stats live in upper half of `out`.
#define CNTS_U  4096
#define W2T_F   4608
#define STATS_OUT_OFF (8u*1024u*1024u)   // floats; out[0..8M)=zg scratch, stats at out[8M..)
#define SLOT_STRIDE 16384                 // 256 blocks x 64 q

__device__ __forceinline__ void mish2(float v, float& mp, float& mn) {
  // mish(v) = v*tanh(softplus(v)) = v*(u^2+2u)/(u^2+2u+2), u=e^v
  // mish(-v) = -v*(2u+1)/(2u^2+2u+1)   (shares u)
  float vc = fminf(fmaxf(v, -30.f), 30.f);
  float u  = __expf(vc);
  float n1 = u * (u + 2.f);
  mp = v * n1 * __builtin_amdgcn_rcpf(n1 + 2.f);
  float n2 = fmaf(2.f, u, 1.f);
  float d2 = fmaf(2.f * u, u, n2);
  mn = -v * n2 * __builtin_amdgcn_rcpf(d2);
}

__device__ __forceinline__ float coherent_ld(const float* p) {
  return __hip_atomic_load(p, __ATOMIC_RELAXED, __HIP_MEMORY_SCOPE_AGENT);
}
__device__ __forceinline__ void coherent_st(float* p, float v) {
  __hip_atomic_store(p, v, __ATOMIC_RELAXED, __HIP_MEMORY_SCOPE_AGENT);
}

// Grid barrier with ZERO shared polled lines:
//  - arrivals: 32 counter lines, 8 RMWs each (parallel LLC banks)
//  - block 0 lane 0 polls the 32 counters (32-deep load batch per round)
//  - broadcast: block 0's 256 threads store gen to 256 PRIVATE flag lines
//  - every other block polls ONLY its own flag line (1 poller per line)
// R0-R2 all had ~255 pollers hammering ONE line -> LLC bank queue saturation
// (~60us/barrier). This removes all same-line polling.
__device__ __forceinline__ void grid_sync(float* ws, unsigned gen, bool flush) {
  __syncthreads();                       // all waves vmcnt(0): prior stores complete
  unsigned* flags = (unsigned*)ws;       // flags[b*16], b = 0..255
  unsigned* cnts  = (unsigned*)ws + CNTS_U;
  if (blockIdx.x == 0) {
    if (threadIdx.x == 0) {
      if (flush) __threadfence();        // final barrier only: wbl2 drains dirty zg lines
      __hip_atomic_fetch_add(&cnts[0], 1u, __ATOMIC_RELAXED, __HIP_MEMORY_SCOPE_AGENT);
      unsigned sum;
      do {
        __builtin_amdgcn_s_sleep(2);
        sum = 0;
        #pragma unroll
        for (int x = 0; x < 32; ++x)
          sum += __hip_atomic_load(&cnts[x*16], __ATOMIC_RELAXED, __HIP_MEMORY_SCOPE_AGENT);
      } while (sum < gen * NBLK);
    }
    __syncthreads();                     // detection done -> broadcast
    __hip_atomic_store(&flags[threadIdx.x * 16], gen,
                       __ATOMIC_RELAXED, __HIP_MEMORY_SCOPE_AGENT);
  } else {
    if (threadIdx.x == 0) {
      if (flush) __threadfence();
      __hip_atomic_fetch_add(&cnts[(blockIdx.x & 31) * 16], 1u,
                             __ATOMIC_RELAXED, __HIP_MEMORY_SCOPE_AGENT);
      while (__hip_atomic_load(&flags[blockIdx.x * 16],
                               __ATOMIC_RELAXED, __HIP_MEMORY_SCOPE_AGENT) < gen)
        __builtin_amdgcn_s_sleep(2);
    }
    __syncthreads();
  }
}

// Per-block reduce of 32 per-thread values -> 64 partials (32 sums + 32 sumsq),
// stored contention-free to this block's private stats row (agent-scope, coalesced).
__device__ __forceinline__ void block_reduce_stats(const float (&vals)[32],
    float* s_red, float* s_p2, float* slot, int t) {
  #pragma unroll
  for (int cc = 0; cc < 8; ++cc) {
    float4 v = make_float4(vals[cc*4+0], vals[cc*4+1], vals[cc*4+2], vals[cc*4+3]);
    *(float4*)(&s_red[t*32 + ((cc ^ (t & 7)) << 2)]) = v;  // xor-swizzle: conflict-free
  }
  __syncthreads();
  {
    int q = t & 63, grp = t >> 6, c = q & 31;
    bool issq = (q >= 32);
    float acc = 0.f;
    #pragma clang loop unroll_count(8)
    for (int rr = 0; rr < 64; ++rr) {
      int row = grp * 64 + rr;
      float v = s_red[row*32 + ((((c >> 2) ^ (row & 7)) << 2) | (c & 3))];
      acc = fmaf(v, issq ? v : 1.f, acc);
    }
    s_p2[t] = acc;   // t == grp*64+q
  }
  __syncthreads();
  if (t < 64) {
    float tot = s_p2[t] + s_p2[t+64] + s_p2[t+128] + s_p2[t+192];
    coherent_st(&slot[blockIdx.x * 64 + t], tot);   // zero-contention store
  }
}

extern "C" __global__ void __launch_bounds__(BS, 1)
qnet_kernel(const float* __restrict__ xin,
            const float* __restrict__ start_w, const float* __restrict__ start_b,
            const float* __restrict__ gate_w,  const float* __restrict__ gate_b,
            const float* __restrict__ res_w,   const float* __restrict__ res_b,
            const float* __restrict__ bn_g,    const float* __restrict__ bn_b,
            const float* __restrict__ e1g,     const float* __restrict__ e1b,
            const float* __restrict__ c1w,     const float* __restrict__ c1b,
            const float* __restrict__ e2g,     const float* __restrict__ e2b,
            const float* __restrict__ c2w,     const float* __restrict__ c2b,
            float* __restrict__ out, float* __restrict__ ws)
{
  __shared__ float s_red[BS*32];
  __shared__ float s_p2[BS];
  __shared__ float s_tot[64];
  __shared__ float s_bcA[128];
  __shared__ float s_bcB[128];

  const int t   = threadIdx.x;
  const int p   = blockIdx.x * BS + t;         // position in [0,65536)
  float* w2t    = ws + W2T_F;
  float* zg     = out;                         // lower 32MB of out = z scratch (own column only)
  float* sg     = out + STATS_OUT_OFF;         // stats region (overwritten only after final barrier)
  unsigned gen  = 0;

  const int bb = p >> 13, ll = p & 8191;
  const int pbase = bb * (256*8192) + ll;

  // transpose end_conv2_w (256x256) -> w2t[k][o]; agent-scope stores (cross-XCD via LLC)
  {
    int o = p & 255, kk = p >> 8;
    coherent_st(&w2t[kk*256 + o], c2w[o*256 + kk]);
  }

  // ---- start conv: x[32] = start_w(32x256) @ xin + start_b
  float x[32];
  #pragma unroll
  for (int j = 0; j < 32; ++j) x[j] = start_b[j];
  #pragma clang loop unroll(disable)
  for (int c8 = 0; c8 < 32; ++c8) {
    float xv[8];
    #pragma unroll
    for (int cc = 0; cc < 8; ++cc) xv[cc] = xin[pbase + (c8*8+cc)*8192];
    #pragma unroll
    for (int j = 0; j < 32; ++j)
      #pragma unroll
      for (int cc = 0; cc < 8; ++cc)
        x[j] = fmaf(start_w[j*256 + c8*8 + cc], xv[cc], x[j]);
  }

  // ---- 40 residual layers (dilate is a pure position permutation -> value no-op)
  #pragma clang loop unroll(disable)
  for (int i = 0; i < 40; ++i) {
    float g[16];
    #pragma unroll
    for (int j = 0; j < 16; ++j) g[j] = gate_b[i*16 + j];
    #pragma unroll
    for (int j = 0; j < 16; ++j)
      #pragma unroll
      for (int k = 0; k < 32; ++k)
        g[j] = fmaf(gate_w[i*512 + j*32 + k], x[k], g[j]);

    float cm[32];
    #pragma unroll
    for (int j = 0; j < 16; ++j) mish2(g[j], cm[j], cm[j+16]);

    float r[32];
    #pragma unroll
    for (int j = 0; j < 32; ++j) r[j] = res_b[i*32 + j];
    #pragma unroll
    for (int j = 0; j < 32; ++j)
      #pragma unroll
      for (int k = 0; k < 32; ++k)
        r[j] = fmaf(res_w[i*1024 + j*32 + k], cm[k], r[j]);

    block_reduce_stats(r, s_red, s_p2, sg + (size_t)i * SLOT_STRIDE, t);
    ++gen; grid_sync(ws, gen, false);

    // 4-wave read-back: wave w sums blocks w*64..w*64+63 for its lane's column q
    {
      int q = t & 63, w = t >> 6;
      const float* col = sg + (size_t)i * SLOT_STRIDE + q;
      float acc2 = 0.f;
      #pragma clang loop unroll_count(16)
      for (int j = 0; j < 64; ++j) acc2 += coherent_ld(&col[(w*64+j)*64]);
      s_p2[t] = acc2;
    }
    __syncthreads();
    if (t < 64) s_tot[t] = s_p2[t] + s_p2[t+64] + s_p2[t+128] + s_p2[t+192];
    __syncthreads();
    if (t < 32) {
      float mean = s_tot[t] * (1.f/65536.f);
      float var  = fmaf(-mean, mean, s_tot[t+32] * (1.f/65536.f));
      float sc   = bn_g[i*32+t] * rsqrtf(var + 1e-5f);
      s_bcA[t] = sc;
      s_bcB[t] = fmaf(-mean, sc, bn_b[i*32+t]);
    }
    __syncthreads();
    #pragma unroll
    for (int c = 0; c < 32; ++c)
      x[c] += fmaf(r[c], s_bcA[c], s_bcB[c]);
  }

  // ---- end: BN1 -> concat_mish (64)
  block_reduce_stats(x, s_red, s_p2, sg + 40 * SLOT_STRIDE, t);
  ++gen; grid_sync(ws, gen, false);
  {
    int q = t & 63, w = t >> 6;
    const float* col = sg + (size_t)40 * SLOT_STRIDE + q;
    float acc2 = 0.f;
    #pragma clang loop unroll_count(16)
    for (int j = 0; j < 64; ++j) acc2 += coherent_ld(&col[(w*64+j)*64]);
    s_p2[t] = acc2;
  }
  __syncthreads();
  if (t < 64) s_tot[t] = s_p2[t] + s_p2[t+64] + s_p2[t+128] + s_p2[t+192];
  __syncthreads();
  if (t < 32) {
    float mean = s_tot[t] * (1.f/65536.f);
    float var  = fmaf(-mean, mean, s_tot[t+32] * (1.f/65536.f));
    float sc   = e1g[t] * rsqrtf(var + 1e-5f);
    s_bcA[t] = sc;
    s_bcB[t] = fmaf(-mean, sc, e1b[t]);
  }
  __syncthreads();
  float mp[32], mn[32];
  #pragma unroll
  for (int c = 0; c < 32; ++c) {
    float xh = fmaf(x[c], s_bcA[c], s_bcB[c]);
    mish2(xh, mp[c], mn[c]);
  }

  // ---- conv1 (128x64) in 4 passes of 32 out-ch; z -> zg (own column) + stats
  #pragma clang loop unroll(disable)
  for (int pp = 0; pp < 4; ++pp) {
    float zc[32];
    #pragma unroll
    for (int j = 0; j < 32; ++j) zc[j] = c1b[pp*32 + j];
    #pragma unroll
    for (int j = 0; j < 32; ++j)
      #pragma unroll
      for (int k = 0; k < 32; ++k) {
        zc[j] = fmaf(c1w[(pp*32+j)*64 + k],      mp[k], zc[j]);
        zc[j] = fmaf(c1w[(pp*32+j)*64 + 32 + k], mn[k], zc[j]);
      }
    #pragma unroll
    for (int j = 0; j < 32; ++j) zg[(pp*32+j)*65536 + p] = zc[j];
    block_reduce_stats(zc, s_red, s_p2, sg + (size_t)(41+pp) * SLOT_STRIDE, t);
    __syncthreads();   // s_red/s_p2 reused next pass
  }
  ++gen; grid_sync(ws, gen, false);

  // e2 read-back: wave w handles slot 41+w, lane q its full 256-element column
  {
    int slot = 41 + (t >> 6), q = t & 63;
    const float* col = sg + (size_t)slot * SLOT_STRIDE + q;
    float acc2 = 0.f;
    #pragma clang loop unroll_count(32)
    for (int b2 = 0; b2 < 256; ++b2) acc2 += coherent_ld(&col[b2*64]);
    s_p2[t] = acc2;
  }
  __syncthreads();
  if (t < 128) {
    float S = s_p2[((t>>5)<<6) | (t&31)];
    float Q = s_p2[((t>>5)<<6) | 32 | (t&31)];
    float mean = S * (1.f/65536.f);
    float var  = fmaf(-mean, mean, Q * (1.f/65536.f));
    float sc   = e2g[t] * rsqrtf(var + 1e-5f);
    s_bcA[t] = sc;
    s_bcB[t] = fmaf(-mean, sc, e2b[t]);
  }
  __syncthreads();

  // ---- conv2 (256x256): acc over all 256 outputs, k dynamic, zv software-prefetched
  float acc[256];
  #pragma unroll
  for (int o = 0; o < 256; ++o) acc[o] = c2b[o];
  float zv_next = zg[p];
  #pragma clang loop unroll(disable)
  for (int k = 0; k < 128; ++k) {
    float zv = zv_next;
    zv_next = zg[((k+1)&127)*65536 + p];
    float zh = fmaf(zv, s_bcA[k], s_bcB[k]);
    float mpv, mnv; mish2(zh, mpv, mnv);
    const float* w0 = &w2t[k*256];
    const float* w1 = &w2t[(k+128)*256];
    #pragma unroll
    for (int o = 0; o < 256; ++o)
      acc[o] = fmaf(w0[o], mpv, fmaf(w1[o], mnv, acc[o]));
  }

  // final barrier WITH flush: wbl2 drains dirty zg lines from every XCD's L2 so the
  // plain final writes below are the only dirty copies (fixes zg/out aliasing race)
  ++gen; grid_sync(ws, gen, true);

  #pragma unroll
  for (int o = 0; o < 256; ++o)
    out[bb*(256*8192) + o*8192 + ll] = acc[o];
}

extern "C" void kernel_launch(void* const* d_in, const int* in_sizes, int n_in,
                              void* d_out, int out_size, void* d_ws, size_t ws_size,
                              hipStream_t stream) {
  // zero flag lines + counter lines: (4096 + 512) dwords
  hipMemsetAsync(d_ws, 0, (CNTS_U + 512) * 4, stream);

  const float* xin = (const float*)d_in[0];
  const float* sw  = (const float*)d_in[1];
  const float* sb  = (const float*)d_in[2];
  const float* gw  = (const float*)d_in[3];
  const float* gb  = (const float*)d_in[4];
  const float* rw  = (const float*)d_in[5];
  const float* rb  = (const float*)d_in[6];
  const float* bng = (const float*)d_in[7];
  const float* bnb = (const float*)d_in[8];
  const float* e1g = (const float*)d_in[9];
  const float* e1b = (const float*)d_in[10];
  const float* c1w = (const float*)d_in[11];
  const float* c1b = (const float*)d_in[12];
  const float* e2g = (const float*)d_in[13];
  const float* e2b = (const float*)d_in[14];
  const float* c2w = (const float*)d_in[15];
  const float* c2b = (const float*)d_in[16];
  float* out = (float*)d_out;
  float* ws  = (float*)d_ws;

  void* args[] = { &xin, &sw, &sb, &gw, &gb, &rw, &rb, &bng, &bnb,
                   &e1g, &e1b, &c1w, &c1b, &e2g, &e2b, &c2w, &c2b, &out, &ws };
  hipError_t err = hipLaunchCooperativeKernel((const void*)qnet_kernel,
                                              dim3(NBLK), dim3(BS), args, 0, stream);
  if (err != hipSuccess) {
    // fallback: plain launch (manual barrier still correct; 256 blocks <= 256 CUs co-resident)
    hipLaunchKernelGGL(qnet_kernel, dim3(NBLK), dim3(BS), 0, stream,
                       xin, sw, sb, gw, gb, rw, rb, bng, bnb,
                       e1g, e1b, c1w, c1b, e2g, e2b, c2w, c2b, out, ws);
  }
}

// Round 5
// 1911.210 us; speedup vs baseline: 1.4748x; 1.3048x over previous
//
#include <hip/hip_runtime.h>

#define BS 256
// ---------- multi-kernel path: ws float layout ----------
// stats: 45 slots x 1024 floats (16 reps x (32 sums + 32 sumsq))
#define STATS_F   0
#define W2T_F     46080            // 65536 floats: transposed end_conv2_w [k][o]
#define XBUF_F    131072           // 2^21 floats: x state [c][p]
#define RBUF_F    2228224          // 2^21 floats: r state [c][p]
#define WS_NEED_BYTES (4325376ull * 4ull)

__device__ __forceinline__ void mish2(float v, float& mp, float& mn) {
  // mish(v) = v*(u^2+2u)/(u^2+2u+2), u=e^v ; mish(-v) = -v*(2u+1)/(2u^2+2u+1)
  float vc = fminf(fmaxf(v, -30.f), 30.f);
  float u  = __expf(vc);
  float n1 = u * (u + 2.f);
  mp = v * n1 * __builtin_amdgcn_rcpf(n1 + 2.f);
  float n2 = fmaf(2.f, u, 1.f);
  float d2 = fmaf(2.f * u, u, n2);
  mn = -v * n2 * __builtin_amdgcn_rcpf(d2);
}

// Per-block reduce of 32 per-thread values -> 32 sums + 32 sumsq, atomically
// added to slot[(blockIdx&15)*64 + q] (16 replicas -> only 16 RMW per address).
__device__ __forceinline__ void block_reduce_stats(const float (&vals)[32],
    float* s_red, float* s_p2, float* slot, int t) {
  #pragma unroll
  for (int cc = 0; cc < 8; ++cc) {
    float4 v = make_float4(vals[cc*4+0], vals[cc*4+1], vals[cc*4+2], vals[cc*4+3]);
    *(float4*)(&s_red[t*32 + ((cc ^ (t & 7)) << 2)]) = v;  // xor-swizzle: conflict-free
  }
  __syncthreads();
  {
    int q = t & 63, grp = t >> 6, c = q & 31;
    bool issq = (q >= 32);
    float acc = 0.f;
    #pragma clang loop unroll_count(8)
    for (int rr = 0; rr < 64; ++rr) {
      int row = grp * 64 + rr;
      float v = s_red[row*32 + ((((c >> 2) ^ (row & 7)) << 2) | (c & 3))];
      acc = fmaf(v, issq ? v : 1.f, acc);
    }
    s_p2[t] = acc;
  }
  __syncthreads();
  if (t < 64) {
    float tot = s_p2[t] + s_p2[t+64] + s_p2[t+128] + s_p2[t+192];
    unsafeAtomicAdd(&slot[(blockIdx.x & 15) * 64 + t], tot);
  }
  __syncthreads();   // allow LDS reuse by caller
}

// Finalize BN over a 32-channel slot (written by previous kernel's atomics).
__device__ __forceinline__ void bn32_from_slot(const float* slot, const float* g,
    const float* b, float* sA, float* sB, float* s_tmp, int t) {
  if (t < 64) {
    float s = 0.f;
    #pragma unroll
    for (int rep = 0; rep < 16; ++rep) s += slot[rep*64 + t];
    s_tmp[t] = s;
  }
  __syncthreads();
  if (t < 32) {
    float mean = s_tmp[t] * (1.f/65536.f);
    float var  = fmaf(-mean, mean, s_tmp[t+32] * (1.f/65536.f));
    float sc   = g[t] * rsqrtf(var + 1e-5f);
    sA[t] = sc;
    sB[t] = fmaf(-mean, sc, b[t]);
  }
  __syncthreads();
}

// Gate->mish->res for layer i from state x; r out.
__device__ __forceinline__ void layer_convs(const float (&x)[32], float (&r)[32],
    const float* gw, const float* gb, const float* rw, const float* rb, int i) {
  float g[16];
  #pragma unroll
  for (int j = 0; j < 16; ++j) g[j] = gb[i*16 + j];
  #pragma unroll
  for (int j = 0; j < 16; ++j)
    #pragma unroll
    for (int k = 0; k < 32; ++k)
      g[j] = fmaf(gw[i*512 + j*32 + k], x[k], g[j]);
  float cm[32];
  #pragma unroll
  for (int j = 0; j < 16; ++j) mish2(g[j], cm[j], cm[j+16]);
  #pragma unroll
  for (int j = 0; j < 32; ++j) r[j] = rb[i*32 + j];
  #pragma unroll
  for (int j = 0; j < 32; ++j)
    #pragma unroll
    for (int k = 0; k < 32; ++k)
      r[j] = fmaf(rw[i*1024 + j*32 + k], cm[k], r[j]);
}

// ---- K_start: w2 transpose + start conv + layer 0 + stats slot 0
__global__ void __launch_bounds__(BS) k_start(const float* __restrict__ xin,
    const float* __restrict__ sw, const float* __restrict__ sb,
    const float* __restrict__ gw, const float* __restrict__ gb,
    const float* __restrict__ rw, const float* __restrict__ rb,
    const float* __restrict__ c2w, float* __restrict__ ws) {
  __shared__ float s_red[BS*32];
  __shared__ float s_p2[BS];
  int t = threadIdx.x, p = blockIdx.x * BS + t;
  float* w2t = ws + W2T_F; float* xb = ws + XBUF_F; float* rbf = ws + RBUF_F;
  { int o = p & 255, kk = p >> 8; w2t[kk*256 + o] = c2w[o*256 + kk]; }
  int bb = p >> 13, ll = p & 8191;
  int pbase = bb * 2097152 + ll;
  float x[32];
  #pragma unroll
  for (int j = 0; j < 32; ++j) x[j] = sb[j];
  #pragma clang loop unroll(disable)
  for (int c8 = 0; c8 < 32; ++c8) {
    float xv[8];
    #pragma unroll
    for (int cc = 0; cc < 8; ++cc) xv[cc] = xin[pbase + (c8*8+cc)*8192];
    #pragma unroll
    for (int j = 0; j < 32; ++j)
      #pragma unroll
      for (int cc = 0; cc < 8; ++cc)
        x[j] = fmaf(sw[j*256 + c8*8 + cc], xv[cc], x[j]);
  }
  float r[32];
  layer_convs(x, r, gw, gb, rw, rb, 0);
  #pragma unroll
  for (int c = 0; c < 32; ++c) { xb[c*65536 + p] = x[c]; rbf[c*65536 + p] = r[c]; }
  block_reduce_stats(r, s_red, s_p2, ws + STATS_F, t);
}

// ---- K_layer(i): apply bn_{i-1} to r_{i-1}, update x, compute r_i + stats slot i
__global__ void __launch_bounds__(BS) k_layer(const float* __restrict__ gw,
    const float* __restrict__ gb, const float* __restrict__ rw,
    const float* __restrict__ rb, const float* __restrict__ bng,
    const float* __restrict__ bnb, float* __restrict__ ws, int i) {
  __shared__ float s_red[BS*32];
  __shared__ float s_p2[BS];
  __shared__ float s_A[32], s_B[32], s_tmp[64];
  int t = threadIdx.x, p = blockIdx.x * BS + t;
  float* stats = ws + STATS_F; float* xb = ws + XBUF_F; float* rbf = ws + RBUF_F;
  bn32_from_slot(stats + (i-1)*1024, bng + (i-1)*32, bnb + (i-1)*32, s_A, s_B, s_tmp, t);
  float x[32], r[32];
  #pragma unroll
  for (int c = 0; c < 32; ++c) { x[c] = xb[c*65536 + p]; r[c] = rbf[c*65536 + p]; }
  #pragma unroll
  for (int c = 0; c < 32; ++c) x[c] += fmaf(r[c], s_A[c], s_B[c]);
  float rn[32];
  layer_convs(x, rn, gw, gb, rw, rb, i);
  #pragma unroll
  for (int c = 0; c < 32; ++c) { xb[c*65536 + p] = x[c]; rbf[c*65536 + p] = rn[c]; }
  block_reduce_stats(rn, s_red, s_p2, stats + i*1024, t);
}

// ---- K_end1: apply bn_39, write final residual x, stats of x -> slot 40
__global__ void __launch_bounds__(BS) k_end1(const float* __restrict__ bng,
    const float* __restrict__ bnb, float* __restrict__ ws) {
  __shared__ float s_red[BS*32];
  __shared__ float s_p2[BS];
  __shared__ float s_A[32], s_B[32], s_tmp[64];
  int t = threadIdx.x, p = blockIdx.x * BS + t;
  float* stats = ws + STATS_F; float* xb = ws + XBUF_F; float* rbf = ws + RBUF_F;
  bn32_from_slot(stats + 39*1024, bng + 39*32, bnb + 39*32, s_A, s_B, s_tmp, t);
  float x[32];
  #pragma unroll
  for (int c = 0; c < 32; ++c) {
    float r = rbf[c*65536 + p];
    x[c] = xb[c*65536 + p] + fmaf(r, s_A[c], s_B[c]);
    xb[c*65536 + p] = x[c];
  }
  block_reduce_stats(x, s_red, s_p2, stats + 40*1024, t);
}

// ---- K_end2: bn1 -> concat_mish -> conv1 (recompute later); stats slots 41..44
__global__ void __launch_bounds__(BS) k_end2(const float* __restrict__ e1g,
    const float* __restrict__ e1b, const float* __restrict__ c1w,
    const float* __restrict__ c1b, float* __restrict__ ws) {
  __shared__ float s_red[BS*32];
  __shared__ float s_p2[BS];
  __shared__ float s_A[32], s_B[32], s_tmp[64];
  int t = threadIdx.x, p = blockIdx.x * BS + t;
  float* stats = ws + STATS_F; float* xb = ws + XBUF_F;
  bn32_from_slot(stats + 40*1024, e1g, e1b, s_A, s_B, s_tmp, t);
  float mp[32], mn[32];
  #pragma unroll
  for (int c = 0; c < 32; ++c) {
    float xh = fmaf(xb[c*65536 + p], s_A[c], s_B[c]);
    mish2(xh, mp[c], mn[c]);
  }
  #pragma clang loop unroll(disable)
  for (int pp = 0; pp < 4; ++pp) {
    float zc[32];
    #pragma unroll
    for (int j = 0; j < 32; ++j) zc[j] = c1b[pp*32 + j];
    #pragma unroll
    for (int j = 0; j < 32; ++j)
      #pragma unroll
      for (int k = 0; k < 32; ++k) {
        zc[j] = fmaf(c1w[(pp*32+j)*64 + k],      mp[k], zc[j]);
        zc[j] = fmaf(c1w[(pp*32+j)*64 + 32 + k], mn[k], zc[j]);
      }
    block_reduce_stats(zc, s_red, s_p2, stats + (41+pp)*1024, t);
  }
}

// ---- K_end3 (grid 256 x 4): recompute z, bn2 -> concat_mish -> conv2 chunk -> out
__global__ void __launch_bounds__(BS) k_end3(const float* __restrict__ e1g,
    const float* __restrict__ e1b, const float* __restrict__ c1w,
    const float* __restrict__ c1b, const float* __restrict__ e2g,
    const float* __restrict__ e2b, const float* __restrict__ c2b,
    float* __restrict__ out, float* __restrict__ ws) {
  __shared__ float s_A[32], s_B[32], s_tmp[64];
  __shared__ float s_A2[128], s_B2[128];
  int t = threadIdx.x, p = blockIdx.x * BS + t;
  float* stats = ws + STATS_F; float* xb = ws + XBUF_F; float* w2t = ws + W2T_F;
  bn32_from_slot(stats + 40*1024, e1g, e1b, s_A, s_B, s_tmp, t);
  if (t < 128) {
    int pp = t >> 5, c = t & 31;
    const float* sl = stats + (41+pp)*1024;
    float S = 0.f, Q = 0.f;
    #pragma unroll
    for (int rep = 0; rep < 16; ++rep) { S += sl[rep*64 + c]; Q += sl[rep*64 + 32 + c]; }
    float mean = S * (1.f/65536.f);
    float var  = fmaf(-mean, mean, Q * (1.f/65536.f));
    float sc   = e2g[t] * rsqrtf(var + 1e-5f);
    s_A2[t] = sc;
    s_B2[t] = fmaf(-mean, sc, e2b[t]);
  }
  __syncthreads();
  float mp[32], mn[32];
  #pragma unroll
  for (int c = 0; c < 32; ++c) {
    float xh = fmaf(xb[c*65536 + p], s_A[c], s_B[c]);
    mish2(xh, mp[c], mn[c]);
  }
  const int ocb = blockIdx.y * 64;
  float acc[64];
  #pragma unroll
  for (int o = 0; o < 64; ++o) acc[o] = c2b[ocb + o];
  #pragma clang loop unroll(disable)
  for (int kc = 0; kc < 4; ++kc) {
    float zc[32];
    #pragma unroll
    for (int j = 0; j < 32; ++j) zc[j] = c1b[kc*32 + j];
    #pragma unroll
    for (int j = 0; j < 32; ++j)
      #pragma unroll
      for (int k = 0; k < 32; ++k) {
        zc[j] = fmaf(c1w[(kc*32+j)*64 + k],      mp[k], zc[j]);
        zc[j] = fmaf(c1w[(kc*32+j)*64 + 32 + k], mn[k], zc[j]);
      }
    #pragma clang loop unroll(disable)
    for (int j = 0; j < 32; ++j) {
      int k = kc*32 + j;
      float zh = fmaf(zc[j], s_A2[k], s_B2[k]);
      float mpv, mnv; mish2(zh, mpv, mnv);
      const float* w0 = &w2t[k*256 + ocb];
      const float* w1 = &w2t[(k+128)*256 + ocb];
      #pragma unroll
      for (int o = 0; o < 64; ++o)
        acc[o] = fmaf(w0[o], mpv, fmaf(w1[o], mnv, acc[o]));
    }
  }
  int bb = p >> 13, ll = p & 8191;
  int obase = bb * 2097152 + ocb * 8192 + ll;
  #pragma unroll
  for (int o = 0; o < 64; ++o) out[obase + o*8192] = acc[o];
}

// =================== fallback: R3 persistent kernel (ws too small) ===================
#define NBLK 256
#define CNTS_U  4096
#define W2T_FB  4608
#define STATS_OUT_OFF (8u*1024u*1024u)
#define SLOT_STRIDE 16384

__device__ __forceinline__ float coherent_ld(const float* p) {
  return __hip_atomic_load(p, __ATOMIC_RELAXED, __HIP_MEMORY_SCOPE_AGENT);
}
__device__ __forceinline__ void coherent_st(float* p, float v) {
  __hip_atomic_store(p, v, __ATOMIC_RELAXED, __HIP_MEMORY_SCOPE_AGENT);
}
__device__ __forceinline__ void grid_sync_fb(float* ws, unsigned gen, bool flush) {
  __syncthreads();
  unsigned* flags = (unsigned*)ws;
  unsigned* cnts  = (unsigned*)ws + CNTS_U;
  if (blockIdx.x == 0) {
    if (threadIdx.x == 0) {
      if (flush) __threadfence();
      __hip_atomic_fetch_add(&cnts[0], 1u, __ATOMIC_RELAXED, __HIP_MEMORY_SCOPE_AGENT);
      unsigned sum;
      do {
        __builtin_amdgcn_s_sleep(2);
        sum = 0;
        #pragma unroll
        for (int x = 0; x < 32; ++x)
          sum += __hip_atomic_load(&cnts[x*16], __ATOMIC_RELAXED, __HIP_MEMORY_SCOPE_AGENT);
      } while (sum < gen * NBLK);
    }
    __syncthreads();
    __hip_atomic_store(&flags[threadIdx.x * 16], gen,
                       __ATOMIC_RELAXED, __HIP_MEMORY_SCOPE_AGENT);
  } else {
    if (threadIdx.x == 0) {
      if (flush) __threadfence();
      __hip_atomic_fetch_add(&cnts[(blockIdx.x & 31) * 16], 1u,
                             __ATOMIC_RELAXED, __HIP_MEMORY_SCOPE_AGENT);
      while (__hip_atomic_load(&flags[blockIdx.x * 16],
                               __ATOMIC_RELAXED, __HIP_MEMORY_SCOPE_AGENT) < gen)
        __builtin_amdgcn_s_sleep(2);
    }
    __syncthreads();
  }
}
__device__ __forceinline__ void brs_fb(const float (&vals)[32],
    float* s_red, float* s_p2, float* slot, int t) {
  #pragma unroll
  for (int cc = 0; cc < 8; ++cc) {
    float4 v = make_float4(vals[cc*4+0], vals[cc*4+1], vals[cc*4+2], vals[cc*4+3]);
    *(float4*)(&s_red[t*32 + ((cc ^ (t & 7)) << 2)]) = v;
  }
  __syncthreads();
  {
    int q = t & 63, grp = t >> 6, c = q & 31;
    bool issq = (q >= 32);
    float acc = 0.f;
    #pragma clang loop unroll_count(8)
    for (int rr = 0; rr < 64; ++rr) {
      int row = grp * 64 + rr;
      float v = s_red[row*32 + ((((c >> 2) ^ (row & 7)) << 2) | (c & 3))];
      acc = fmaf(v, issq ? v : 1.f, acc);
    }
    s_p2[t] = acc;
  }
  __syncthreads();
  if (t < 64) {
    float tot = s_p2[t] + s_p2[t+64] + s_p2[t+128] + s_p2[t+192];
    coherent_st(&slot[blockIdx.x * 64 + t], tot);
  }
}

extern "C" __global__ void __launch_bounds__(BS, 1)
qnet_fb(const float* __restrict__ xin,
        const float* __restrict__ sw, const float* __restrict__ sb,
        const float* __restrict__ gw, const float* __restrict__ gb,
        const float* __restrict__ rw, const float* __restrict__ rb,
        const float* __restrict__ bng, const float* __restrict__ bnb,
        const float* __restrict__ e1g, const float* __restrict__ e1b,
        const float* __restrict__ c1w, const float* __restrict__ c1b,
        const float* __restrict__ e2g, const float* __restrict__ e2b,
        const float* __restrict__ c2w, const float* __restrict__ c2b,
        float* __restrict__ out, float* __restrict__ ws)
{
  __shared__ float s_red[BS*32];
  __shared__ float s_p2[BS];
  __shared__ float s_tot[64];
  __shared__ float s_bcA[128];
  __shared__ float s_bcB[128];
  const int t = threadIdx.x;
  const int p = blockIdx.x * BS + t;
  float* w2t = ws + W2T_FB;
  float* zg  = out;
  float* sg  = out + STATS_OUT_OFF;
  unsigned gen = 0;
  const int bb = p >> 13, ll = p & 8191;
  const int pbase = bb * 2097152 + ll;
  { int o = p & 255, kk = p >> 8; coherent_st(&w2t[kk*256 + o], c2w[o*256 + kk]); }
  float x[32];
  #pragma unroll
  for (int j = 0; j < 32; ++j) x[j] = sb[j];
  #pragma clang loop unroll(disable)
  for (int c8 = 0; c8 < 32; ++c8) {
    float xv[8];
    #pragma unroll
    for (int cc = 0; cc < 8; ++cc) xv[cc] = xin[pbase + (c8*8+cc)*8192];
    #pragma unroll
    for (int j = 0; j < 32; ++j)
      #pragma unroll
      for (int cc = 0; cc < 8; ++cc)
        x[j] = fmaf(sw[j*256 + c8*8 + cc], xv[cc], x[j]);
  }
  #pragma clang loop unroll(disable)
  for (int i = 0; i < 40; ++i) {
    float r[32];
    layer_convs(x, r, gw, gb, rw, rb, i);
    brs_fb(r, s_red, s_p2, sg + (size_t)i * SLOT_STRIDE, t);
    ++gen; grid_sync_fb(ws, gen, false);
    {
      int q = t & 63, w = t >> 6;
      const float* col = sg + (size_t)i * SLOT_STRIDE + q;
      float acc2 = 0.f;
      #pragma clang loop unroll_count(16)
      for (int j = 0; j < 64; ++j) acc2 += coherent_ld(&col[(w*64+j)*64]);
      s_p2[t] = acc2;
    }
    __syncthreads();
    if (t < 64) s_tot[t] = s_p2[t] + s_p2[t+64] + s_p2[t+128] + s_p2[t+192];
    __syncthreads();
    if (t < 32) {
      float mean = s_tot[t] * (1.f/65536.f);
      float var  = fmaf(-mean, mean, s_tot[t+32] * (1.f/65536.f));
      float sc   = bng[i*32+t] * rsqrtf(var + 1e-5f);
      s_bcA[t] = sc;
      s_bcB[t] = fmaf(-mean, sc, bnb[i*32+t]);
    }
    __syncthreads();
    #pragma unroll
    for (int c = 0; c < 32; ++c) x[c] += fmaf(r[c], s_bcA[c], s_bcB[c]);
  }
  brs_fb(x, s_red, s_p2, sg + 40 * SLOT_STRIDE, t);
  ++gen; grid_sync_fb(ws, gen, false);
  {
    int q = t & 63, w = t >> 6;
    const float* col = sg + (size_t)40 * SLOT_STRIDE + q;
    float acc2 = 0.f;
    #pragma clang loop unroll_count(16)
    for (int j = 0; j < 64; ++j) acc2 += coherent_ld(&col[(w*64+j)*64]);
    s_p2[t] = acc2;
  }
  __syncthreads();
  if (t < 64) s_tot[t] = s_p2[t] + s_p2[t+64] + s_p2[t+128] + s_p2[t+192];
  __syncthreads();
  if (t < 32) {
    float mean = s_tot[t] * (1.f/65536.f);
    float var  = fmaf(-mean, mean, s_tot[t+32] * (1.f/65536.f));
    float sc   = e1g[t] * rsqrtf(var + 1e-5f);
    s_bcA[t] = sc;
    s_bcB[t] = fmaf(-mean, sc, e1b[t]);
  }
  __syncthreads();
  float mp[32], mn[32];
  #pragma unroll
  for (int c = 0; c < 32; ++c) {
    float xh = fmaf(x[c], s_bcA[c], s_bcB[c]);
    mish2(xh, mp[c], mn[c]);
  }
  #pragma clang loop unroll(disable)
  for (int pp = 0; pp < 4; ++pp) {
    float zc[32];
    #pragma unroll
    for (int j = 0; j < 32; ++j) zc[j] = c1b[pp*32 + j];
    #pragma unroll
    for (int j = 0; j < 32; ++j)
      #pragma unroll
      for (int k = 0; k < 32; ++k) {
        zc[j] = fmaf(c1w[(pp*32+j)*64 + k],      mp[k], zc[j]);
        zc[j] = fmaf(c1w[(pp*32+j)*64 + 32 + k], mn[k], zc[j]);
      }
    #pragma unroll
    for (int j = 0; j < 32; ++j) zg[(pp*32+j)*65536 + p] = zc[j];
    brs_fb(zc, s_red, s_p2, sg + (size_t)(41+pp) * SLOT_STRIDE, t);
    __syncthreads();
  }
  ++gen; grid_sync_fb(ws, gen, false);
  {
    int slot = 41 + (t >> 6), q = t & 63;
    const float* col = sg + (size_t)slot * SLOT_STRIDE + q;
    float acc2 = 0.f;
    #pragma clang loop unroll_count(32)
    for (int b2 = 0; b2 < 256; ++b2) acc2 += coherent_ld(&col[b2*64]);
    s_p2[t] = acc2;
  }
  __syncthreads();
  if (t < 128) {
    float S = s_p2[((t>>5)<<6) | (t&31)];
    float Q = s_p2[((t>>5)<<6) | 32 | (t&31)];
    float mean = S * (1.f/65536.f);
    float var  = fmaf(-mean, mean, Q * (1.f/65536.f));
    float sc   = e2g[t] * rsqrtf(var + 1e-5f);
    s_bcA[t] = sc;
    s_bcB[t] = fmaf(-mean, sc, e2b[t]);
  }
  __syncthreads();
  float acc[256];
  #pragma unroll
  for (int o = 0; o < 256; ++o) acc[o] = c2b[o];
  float zv_next = zg[p];
  #pragma clang loop unroll(disable)
  for (int k = 0; k < 128; ++k) {
    float zv = zv_next;
    zv_next = zg[((k+1)&127)*65536 + p];
    float zh = fmaf(zv, s_bcA[k], s_bcB[k]);
    float mpv, mnv; mish2(zh, mpv, mnv);
    const float* w0 = &w2t[k*256];
    const float* w1 = &w2t[(k+128)*256];
    #pragma unroll
    for (int o = 0; o < 256; ++o)
      acc[o] = fmaf(w0[o], mpv, fmaf(w1[o], mnv, acc[o]));
  }
  ++gen; grid_sync_fb(ws, gen, true);
  #pragma unroll
  for (int o = 0; o < 256; ++o)
    out[bb*2097152 + o*8192 + ll] = acc[o];
}

extern "C" void kernel_launch(void* const* d_in, const int* in_sizes, int n_in,
                              void* d_out, int out_size, void* d_ws, size_t ws_size,
                              hipStream_t stream) {
  const float* xin = (const float*)d_in[0];
  const float* sw  = (const float*)d_in[1];
  const float* sb  = (const float*)d_in[2];
  const float* gw  = (const float*)d_in[3];
  const float* gb  = (const float*)d_in[4];
  const float* rw  = (const float*)d_in[5];
  const float* rb  = (const float*)d_in[6];
  const float* bng = (const float*)d_in[7];
  const float* bnb = (const float*)d_in[8];
  const float* e1g = (const float*)d_in[9];
  const float* e1b = (const float*)d_in[10];
  const float* c1w = (const float*)d_in[11];
  const float* c1b = (const float*)d_in[12];
  const float* e2g = (const float*)d_in[13];
  const float* e2b = (const float*)d_in[14];
  const float* c2w = (const float*)d_in[15];
  const float* c2b = (const float*)d_in[16];
  float* out = (float*)d_out;
  float* ws  = (float*)d_ws;

  if (ws_size >= WS_NEED_BYTES) {
    // multi-kernel graph: 43 launches; kernel boundaries provide all sync
    hipMemsetAsync(d_ws, 0, 45 * 1024 * 4, stream);
    k_start<<<256, BS, 0, stream>>>(xin, sw, sb, gw, gb, rw, rb, c2w, ws);
    for (int i = 1; i < 40; ++i)
      k_layer<<<256, BS, 0, stream>>>(gw, gb, rw, rb, bng, bnb, ws, i);
    k_end1<<<256, BS, 0, stream>>>(bng, bnb, ws);
    k_end2<<<256, BS, 0, stream>>>(e1g, e1b, c1w, c1b, ws);
    k_end3<<<dim3(256, 4), BS, 0, stream>>>(e1g, e1b, c1w, c1b, e2g, e2b, c2b, out, ws);
  } else {
    // fallback: R3 persistent cooperative kernel (proven, ~2.5 ms)
    hipMemsetAsync(d_ws, 0, (CNTS_U + 512) * 4, stream);
    void* args[] = { &xin, &sw, &sb, &gw, &gb, &rw, &rb, &bng, &bnb,
                     &e1g, &e1b, &c1w, &c1b, &e2g, &e2b, &c2w, &c2b, &out, &ws };
    hipError_t err = hipLaunchCooperativeKernel((const void*)qnet_fb,
                                                dim3(NBLK), dim3(BS), args, 0, stream);
    if (err != hipSuccess) {
      hipLaunchKernelGGL(qnet_fb, dim3(NBLK), dim3(BS), 0, stream,
                         xin, sw, sb, gw, gb, rw, rb, bng, bnb,
                         e1g, e1b, c1w, c1b, e2g, e2b, c2w, c2b, out, ws);
    }
  }
}